// Round 3
// baseline (250.958 us; speedup 1.0000x reference)
//
#include <hip/hip_runtime.h>
#include <hip/hip_bf16.h>

// Problem: B=4, S=2048, D=512. Inputs fp32, OUTPUT fp32 (reference dtype).
// Internal compute bf16 MFMA (threshold = 2% of max|ref| -- ample headroom).
// Pipeline:
//   cvt: q,k,v,W* fp32 -> bf16 copies in ws
//   qp = q@WQ^T+b, kp = k@WK^T+b          (NT GEMM, EPI_BIAS, fp32 bias)
//   vpT = (v@WV^T+b)^T per batch          (NT GEMM, EPI_BIAS_T)
//   E  = exp(mask(scale*qp@kp^T)), masked (q<k) entries = exp(0)=1
//   Z[b][k] = sum_q E[b][q][k]            (softmax over QUERY axis)
//   vpT[b][d][k] /= Z[b][k]
//   out = E @ vpT^T                       (NT GEMM, EPI_PLAIN, fp32 out)

#define S_LEN 2048
#define D_DIM 512
#define SCALE_F 0.044194173824159216f  // 1/sqrt(512)

typedef __attribute__((ext_vector_type(8))) short s8v;   // 8 bf16 in 4 VGPRs
typedef __attribute__((ext_vector_type(4))) float f4v;   // MFMA accumulator

#define BM 128
#define BN 128
#define BK 32
#define LDS_K 40   // padded LDS row stride (bf16): 80B rows, 16B-aligned, conflict-free b128

enum { EPI_BIAS = 0, EPI_BIAS_T = 1, EPI_SCORES = 2, EPI_PLAIN = 3 };

// fp32 -> bf16 (RNE), 4 elems/thread.
__global__ __launch_bounds__(256) void cvt_f32_bf16(
    const float* __restrict__ src, __hip_bfloat16* __restrict__ dst, int n)
{
  const int i = (blockIdx.x * 256 + threadIdx.x) * 4;
  if (i >= n) return;
  const float4 f = *(const float4*)(src + i);
  dst[i + 0] = __float2bfloat16(f.x);
  dst[i + 1] = __float2bfloat16(f.y);
  dst[i + 2] = __float2bfloat16(f.z);
  dst[i + 3] = __float2bfloat16(f.w);
}

// NT GEMM: C[m][n] = sum_k A[m][k]*B[n][k] (+ epilogue). lda = ldb = K.
// EPI_PLAIN writes fp32 (d_out); others write bf16 (internal buffers).
template <int EPI>
__global__ __launch_bounds__(256, 2) void gemm_nt(
    const short* __restrict__ A, const short* __restrict__ B,
    void* __restrict__ Cv, const float* __restrict__ bias,
    int M, int N, int K,
    long long sA, long long sB, long long sC)
{
  __shared__ __align__(16) short As[BM * LDS_K];
  __shared__ __align__(16) short Bs[BN * LDS_K];

  const int tid = threadIdx.x;
  const int bz  = blockIdx.z;
  const int m0  = blockIdx.y * BM;
  const int n0  = blockIdx.x * BN;

  A += (size_t)bz * sA;
  B += (size_t)bz * sB;
  const size_t sCz = (size_t)bz * sC;

  const int w    = tid >> 6;       // wave 0..3
  const int lane = tid & 63;
  const int quad = lane >> 4;      // 0..3
  const int l16  = lane & 15;
  const int wm   = (w >> 1) * 64;  // wave row offset in block tile
  const int wn   = (w & 1) * 64;   // wave col offset

  // staging map: 256 threads x 16B; tile 128x32 bf16 = 8KB -> 2 rows/thread
  const int sr = tid >> 2;         // 0..63
  const int sc = (tid & 3) * 8;    // 0,8,16,24

  f4v acc[4][4];
#pragma unroll
  for (int i = 0; i < 4; ++i)
#pragma unroll
    for (int j = 0; j < 4; ++j)
#pragma unroll
      for (int r = 0; r < 4; ++r) acc[i][j][r] = 0.0f;

  const short* Ag = A + (size_t)(m0 + sr) * K + sc;
  const short* Bg = B + (size_t)(n0 + sr) * K + sc;

  for (int k0 = 0; k0 < K; k0 += BK) {
    *(s8v*)&As[sr * LDS_K + sc]        = *(const s8v*)(Ag + k0);
    *(s8v*)&As[(sr + 64) * LDS_K + sc] = *(const s8v*)(Ag + (size_t)64 * K + k0);
    *(s8v*)&Bs[sr * LDS_K + sc]        = *(const s8v*)(Bg + k0);
    *(s8v*)&Bs[(sr + 64) * LDS_K + sc] = *(const s8v*)(Bg + (size_t)64 * K + k0);
    __syncthreads();

    s8v af[4], bf[4];
#pragma unroll
    for (int i = 0; i < 4; ++i)
      af[i] = *(const s8v*)&As[(wm + i * 16 + l16) * LDS_K + quad * 8];
#pragma unroll
    for (int j = 0; j < 4; ++j)
      bf[j] = *(const s8v*)&Bs[(wn + j * 16 + l16) * LDS_K + quad * 8];

#pragma unroll
    for (int i = 0; i < 4; ++i)
#pragma unroll
      for (int j = 0; j < 4; ++j)
        acc[i][j] = __builtin_amdgcn_mfma_f32_16x16x32_bf16(af[i], bf[j], acc[i][j], 0, 0, 0);

    __syncthreads();
  }

  // ---- epilogue ----
  __hip_bfloat16* C = (__hip_bfloat16*)Cv;
  float* Cf = (float*)Cv;

  float bv[4];
  if (EPI == EPI_BIAS || EPI == EPI_BIAS_T) {
#pragma unroll
    for (int j = 0; j < 4; ++j)
      bv[j] = bias[n0 + wn + j * 16 + l16];
  }

#pragma unroll
  for (int i = 0; i < 4; ++i) {
#pragma unroll
    for (int j = 0; j < 4; ++j) {
      const int gn = n0 + wn + j * 16 + l16;
#pragma unroll
      for (int r = 0; r < 4; ++r) {
        const int gm = m0 + wm + i * 16 + quad * 4 + r;  // C/D: col=lane&15, row=quad*4+reg
        const float v = acc[i][j][r];
        if (EPI == EPI_BIAS) {
          C[(size_t)gm * N + gn] = __float2bfloat16(v + bv[j]);
        } else if (EPI == EPI_BIAS_T) {
          // gm indexes flattened [B*S]; write vpT[b][gn][s]
          const int bb = gm >> 11, ss = gm & (S_LEN - 1);
          C[((size_t)bb * D_DIM + gn) * S_LEN + ss] = __float2bfloat16(v + bv[j]);
        } else if (EPI == EPI_SCORES) {
          // multiplicative causal mask: masked (q<k) entries are 0 -> exp(0)=1
          const float e = (gm >= gn) ? __expf(v * SCALE_F) : 1.0f;
          C[sCz + (size_t)gm * N + gn] = __float2bfloat16(e);
        } else {  // EPI_PLAIN: fp32 output
          Cf[sCz + (size_t)gm * N + gn] = v;
        }
      }
    }
  }
}

// Z[b][k] = sum_q E[b][q][k]. grid: x=colchunk(8 x 256), y=rowchunk(16 x 128), z=batch
__global__ __launch_bounds__(256) void colsum_kernel(
    const __hip_bfloat16* __restrict__ E, float* __restrict__ Z)
{
  const int b = blockIdx.z;
  const int k = blockIdx.x * 256 + threadIdx.x;
  const int q0 = blockIdx.y * 128;
  const __hip_bfloat16* p = E + ((size_t)b * S_LEN + q0) * S_LEN + k;
  float s = 0.0f;
#pragma unroll 8
  for (int i = 0; i < 128; ++i) s += __bfloat162float(p[(size_t)i * S_LEN]);
  atomicAdd(&Z[b * S_LEN + k], s);
}

// vpT[b][d][k] *= 1/Z[b][k]
__global__ __launch_bounds__(256) void scale_vpt_kernel(
    __hip_bfloat16* __restrict__ vpT, const float* __restrict__ Z)
{
  const size_t idx = (size_t)blockIdx.x * 256 + threadIdx.x;  // < 4*512*2048 = 2^22
  const int k = idx & (S_LEN - 1);
  const int b = (int)(idx >> 20);  // idx / (512*2048)
  const float w = 1.0f / Z[b * S_LEN + k];
  vpT[idx] = __float2bfloat16(__bfloat162float(vpT[idx]) * w);
}

extern "C" void kernel_launch(void* const* d_in, const int* in_sizes, int n_in,
                              void* d_out, int out_size, void* d_ws, size_t ws_size,
                              hipStream_t stream) {
  const float* q   = (const float*)d_in[0];
  const float* k   = (const float*)d_in[1];
  const float* v   = (const float*)d_in[2];
  const float* WQw = (const float*)d_in[3];
  const float* WQb = (const float*)d_in[4];
  const float* WKw = (const float*)d_in[5];
  const float* WKb = (const float*)d_in[6];
  const float* WVw = (const float*)d_in[7];
  const float* WVb = (const float*)d_in[8];

  char* ws = (char*)d_ws;
  // E occupies [0, 32M); the bf16 input copies alias its head (dead before E written)
  short* E   = (short*)(ws);                 // 32 MB  [4][2048][2048] bf16
  short* qb  = (short*)(ws);                 //  8 MB  [8192][512] bf16
  short* kb  = (short*)(ws + 8388608);       //  8 MB
  short* vb  = (short*)(ws + 16777216);      //  8 MB
  short* Wqb = (short*)(ws + 25165824);      // 512 KB [512][512] bf16
  short* Wkb = (short*)(ws + 25690112);      // 512 KB
  short* Wvb = (short*)(ws + 26214400);      // 512 KB
  short* qp  = (short*)(ws + 33554432);      //  8 MB  [8192][512] bf16
  short* kp  = (short*)(ws + 41943040);      //  8 MB
  short* vpT = (short*)(ws + 50331648);      //  8 MB  [4][512][2048] bf16
  float* Z   = (float*)(ws + 58720256);      // 32 KB  [4][2048] f32

  const dim3 blk(256);
  const int nBig = 4 * S_LEN * D_DIM;   // 4,194,304
  const int nW   = D_DIM * D_DIM;       // 262,144

  // fp32 -> bf16 conversions
  cvt_f32_bf16<<<dim3(nBig / 1024), blk, 0, stream>>>(q, (__hip_bfloat16*)qb, nBig);
  cvt_f32_bf16<<<dim3(nBig / 1024), blk, 0, stream>>>(k, (__hip_bfloat16*)kb, nBig);
  cvt_f32_bf16<<<dim3(nBig / 1024), blk, 0, stream>>>(v, (__hip_bfloat16*)vb, nBig);
  cvt_f32_bf16<<<dim3(nW / 1024),   blk, 0, stream>>>(WQw, (__hip_bfloat16*)Wqb, nW);
  cvt_f32_bf16<<<dim3(nW / 1024),   blk, 0, stream>>>(WKw, (__hip_bfloat16*)Wkb, nW);
  cvt_f32_bf16<<<dim3(nW / 1024),   blk, 0, stream>>>(WVw, (__hip_bfloat16*)Wvb, nW);

  // projections: M=8192, N=512, K=512 (fp32 bias added in epilogue)
  gemm_nt<EPI_BIAS><<<dim3(4, 64, 1), blk, 0, stream>>>(
      qb, Wqb, qp, WQb, 8192, 512, 512, 0, 0, 0);
  gemm_nt<EPI_BIAS><<<dim3(4, 64, 1), blk, 0, stream>>>(
      kb, Wkb, kp, WKb, 8192, 512, 512, 0, 0, 0);
  gemm_nt<EPI_BIAS_T><<<dim3(4, 64, 1), blk, 0, stream>>>(
      vb, Wvb, vpT, WVb, 8192, 512, 512, 0, 0, 0);

  // scores + mask + exp: per batch M=N=2048, K=512 (overwrites dead input copies)
  gemm_nt<EPI_SCORES><<<dim3(16, 16, 4), blk, 0, stream>>>(
      qp, kp, E, nullptr, 2048, 2048, 512,
      (long long)S_LEN * D_DIM, (long long)S_LEN * D_DIM, (long long)S_LEN * S_LEN);

  // column sums (softmax over query axis) -> Z
  hipMemsetAsync(Z, 0, 4 * S_LEN * sizeof(float), stream);
  colsum_kernel<<<dim3(8, 16, 4), blk, 0, stream>>>((const __hip_bfloat16*)E, Z);

  // fold 1/Z into vp rows
  scale_vpt_kernel<<<dim3(16384), blk, 0, stream>>>((__hip_bfloat16*)vpT, Z);

  // out = E @ vpT': per batch M=2048, N=512, K=2048 (fp32 output)
  gemm_nt<EPI_PLAIN><<<dim3(4, 16, 4), blk, 0, stream>>>(
      E, vpT, d_out, nullptr, 2048, 512, 2048,
      (long long)S_LEN * S_LEN, (long long)D_DIM * S_LEN, (long long)S_LEN * D_DIM);
}

// Round 4
// 235.942 us; speedup vs baseline: 1.0636x; 1.0636x over previous
//
#include <hip/hip_runtime.h>
#include <hip/hip_bf16.h>

// B=4, S=2048, D=512. fp32 in/out, bf16 MFMA internals.
//   cvt: q,k,v,W* fp32 -> bf16
//   proj3: qp = q@WQ^T+b, kp = k@WK^T+b, vpT = (v@WV^T+b)^T  (one launch, z=0..2)
//   scores: E = exp(mask(scale*qp@kp^T)) bf16, masked(q<k)=1; fused Z[k]=sum_q E[q][k]
//   scale:  vpT[b][d][k] /= Z[b][k]
//   out:    E @ vpT^T -> fp32 d_out (split-K=4, atomicAdd into zeroed d_out)
// GEMM core: m97-style 128x128 tile, BK=32, global_load_lds width-16 staging,
// XOR-swizzled column groups so ds_read_b128 is bank-conflict-free.

#define S_LEN 2048
#define D_DIM 512
#define SCALE_F 0.044194173824159216f  // 1/sqrt(512)

typedef __attribute__((ext_vector_type(8))) short s8v;   // 8 bf16 = 4 VGPRs
typedef __attribute__((ext_vector_type(4))) float f4v;   // MFMA accumulator

enum { EPI_BIAS = 0, EPI_BIAS_T = 1, EPI_SCORES = 2, EPI_PLAIN = 3 };

__device__ __forceinline__ short f2bf_s(float f) {
  union { __hip_bfloat16 b; short s; } u; u.b = __float2bfloat16(f); return u.s;
}
__device__ __forceinline__ float bf2f_s(short h) {
  union { short s; __hip_bfloat16 b; } u; u.s = h; return __bfloat162float(u.b);
}

__device__ __forceinline__ void glds16(const short* g, short* l) {
  __builtin_amdgcn_global_load_lds((const __attribute__((address_space(1))) void*)g,
                                   (__attribute__((address_space(3))) void*)l, 16, 0, 0);
}

// Core NT GEMM on a 128x128 tile at (m0,n0), K-range [kBeg,kEnd).
// A,B already offset to this batch. LDS As/Bs: 128x32 bf16, unpadded.
template <int EPI>
__device__ __forceinline__ void gemm_core(
    const short* __restrict__ A, const short* __restrict__ B,
    void* __restrict__ Cv, const float* __restrict__ bias,
    short* As, short* Bs,
    int N, int K, int kBeg, int kEnd,
    size_t sCz, int m0, int n0, int bz, float* __restrict__ Z)
{
  const int tid  = threadIdx.x;
  const int w    = tid >> 6;
  const int lane = tid & 63;
  const int quad = lane >> 4;
  const int l16  = lane & 15;
  const int wm   = (w >> 1) * 64;
  const int wn   = (w & 1) * 64;

  // staging: thread -> (row = tid>>2, phys 16B slot = tid&3); the slot holds
  // logical column-group g = slot ^ (r&3) ^ ((r>>2)&3)  (bank-conflict swizzle)
  const int sr = tid >> 2;                                            // 0..63
  const int g8 = (((tid & 3) ^ ((tid >> 2) & 3) ^ ((tid >> 4) & 3))) * 8;

  f4v acc[4][4];
#pragma unroll
  for (int i = 0; i < 4; ++i)
#pragma unroll
    for (int j = 0; j < 4; ++j)
#pragma unroll
      for (int r = 0; r < 4; ++r) acc[i][j][r] = 0.0f;

  const short* Ag = A + (size_t)(m0 + sr) * K + g8;
  const short* Bg = B + (size_t)(n0 + sr) * K + g8;
  short* Asl = As + tid * 8;   // lane-0-of-wave value is the wave LDS base
  short* Bsl = Bs + tid * 8;
  const size_t rowskip = (size_t)64 * K;

  // read-side swizzle: depends only on l16 (row mod 16)
  const int sw = ((l16 & 3) ^ ((l16 >> 2) & 3)) * 8;

  for (int k0 = kBeg; k0 < kEnd; k0 += 32) {
    glds16(Ag + k0,           Asl);
    glds16(Ag + k0 + rowskip, Asl + 2048);
    glds16(Bg + k0,           Bsl);
    glds16(Bg + k0 + rowskip, Bsl + 2048);
    __syncthreads();

    s8v af[4], bf[4];
#pragma unroll
    for (int i = 0; i < 4; ++i)
      af[i] = *(const s8v*)&As[(wm + i * 16 + l16) * 32 + ((quad * 8) ^ sw)];
#pragma unroll
    for (int j = 0; j < 4; ++j)
      bf[j] = *(const s8v*)&Bs[(wn + j * 16 + l16) * 32 + ((quad * 8) ^ sw)];

#pragma unroll
    for (int i = 0; i < 4; ++i)
#pragma unroll
      for (int j = 0; j < 4; ++j)
        acc[i][j] = __builtin_amdgcn_mfma_f32_16x16x32_bf16(af[i], bf[j], acc[i][j], 0, 0, 0);

    __syncthreads();
  }

  // ---- epilogue ----
  __hip_bfloat16* C = (__hip_bfloat16*)Cv;
  float* Cf = (float*)Cv;

  if (EPI == EPI_SCORES) {
#pragma unroll
    for (int j = 0; j < 4; ++j) {
      const int gn = n0 + wn + j * 16 + l16;
      float csum = 0.0f;
#pragma unroll
      for (int i = 0; i < 4; ++i) {
#pragma unroll
        for (int r = 0; r < 4; ++r) {
          const int gm = m0 + wm + i * 16 + quad * 4 + r;  // C/D: col=l16, row=quad*4+r
          const float e = (gm >= gn) ? __expf(acc[i][j][r] * SCALE_F) : 1.0f;
          csum += e;
          C[sCz + (size_t)gm * N + gn] = __float2bfloat16(e);
        }
      }
      // this wave holds 64 of the 128 tile rows for column gn: reduce across quads
      csum += __shfl_xor(csum, 16, 64);
      csum += __shfl_xor(csum, 32, 64);
      if (quad == 0) atomicAdd(&Z[(bz << 11) + gn], csum);
    }
    return;
  }

  float bv[4];
  if (EPI == EPI_BIAS || EPI == EPI_BIAS_T) {
#pragma unroll
    for (int j = 0; j < 4; ++j) bv[j] = bias[n0 + wn + j * 16 + l16];
  }

#pragma unroll
  for (int i = 0; i < 4; ++i) {
#pragma unroll
    for (int j = 0; j < 4; ++j) {
      const int gn = n0 + wn + j * 16 + l16;
#pragma unroll
      for (int r = 0; r < 4; ++r) {
        const int gm = m0 + wm + i * 16 + quad * 4 + r;
        const float v = acc[i][j][r];
        if (EPI == EPI_BIAS) {
          C[(size_t)gm * N + gn] = __float2bfloat16(v + bv[j]);
        } else if (EPI == EPI_BIAS_T) {
          const int bb = gm >> 11, ss = gm & (S_LEN - 1);
          C[((size_t)bb * D_DIM + gn) * S_LEN + ss] = __float2bfloat16(v + bv[j]);
        } else {  // EPI_PLAIN, split-K partial -> fp32 atomic accumulate
          atomicAdd(&Cf[sCz + (size_t)gm * N + gn], v);
        }
      }
    }
  }
}

template <int EPI, int KSPLIT>
__global__ __launch_bounds__(256, 2) void gemm_nt(
    const short* __restrict__ A, const short* __restrict__ B,
    void* __restrict__ Cv, const float* __restrict__ bias,
    int N, int K, long long sA, long long sB, long long sC,
    float* __restrict__ Z)
{
  __shared__ __align__(16) short As[128 * 32];
  __shared__ __align__(16) short Bs[128 * 32];
  const int z  = blockIdx.z;
  const int bz = z / KSPLIT, kz = z % KSPLIT;
  const int KS = K / KSPLIT;
  gemm_core<EPI>(A + (size_t)bz * sA, B + (size_t)bz * sB, Cv, bias, As, Bs,
                 N, K, kz * KS, kz * KS + KS, (size_t)bz * sC,
                 blockIdx.y * 128, blockIdx.x * 128, bz, Z);
}

// three projections in one launch: z=0 -> qp, z=1 -> kp, z=2 -> vpT (transposed write)
__global__ __launch_bounds__(256, 2) void proj3(
    const short* __restrict__ a0, const short* __restrict__ a1, const short* __restrict__ a2,
    const short* __restrict__ b0, const short* __restrict__ b1, const short* __restrict__ b2,
    short* __restrict__ c0, short* __restrict__ c1, short* __restrict__ c2,
    const float* __restrict__ x0, const float* __restrict__ x1, const float* __restrict__ x2)
{
  __shared__ __align__(16) short As[128 * 32];
  __shared__ __align__(16) short Bs[128 * 32];
  const int z = blockIdx.z;
  const short* A = (z == 0) ? a0 : (z == 1) ? a1 : a2;
  const short* B = (z == 0) ? b0 : (z == 1) ? b1 : b2;
  void*        C = (z == 0) ? (void*)c0 : (z == 1) ? (void*)c1 : (void*)c2;
  const float* bias = (z == 0) ? x0 : (z == 1) ? x1 : x2;
  if (z == 2)
    gemm_core<EPI_BIAS_T>(A, B, C, bias, As, Bs, 512, 512, 0, 512, 0,
                          blockIdx.y * 128, blockIdx.x * 128, 0, nullptr);
  else
    gemm_core<EPI_BIAS>(A, B, C, bias, As, Bs, 512, 512, 0, 512, 0,
                        blockIdx.y * 128, blockIdx.x * 128, 0, nullptr);
}

// fp32 -> bf16, 8 elems/thread, three source arrays -> contiguous dst slabs
__global__ __launch_bounds__(256) void cvt3(
    const float* __restrict__ s0, const float* __restrict__ s1,
    const float* __restrict__ s2, short* __restrict__ dst, int n)
{
  const float* s = (blockIdx.y == 0) ? s0 : (blockIdx.y == 1) ? s1 : s2;
  short* d = dst + (size_t)blockIdx.y * n;
  const int i = (blockIdx.x * 256 + threadIdx.x) * 8;
  if (i >= n) return;
  const float4 f0 = *(const float4*)(s + i);
  const float4 f1 = *(const float4*)(s + i + 4);
  s8v o;
  o[0] = f2bf_s(f0.x); o[1] = f2bf_s(f0.y); o[2] = f2bf_s(f0.z); o[3] = f2bf_s(f0.w);
  o[4] = f2bf_s(f1.x); o[5] = f2bf_s(f1.y); o[6] = f2bf_s(f1.z); o[7] = f2bf_s(f1.w);
  *(s8v*)(d + i) = o;
}

// vpT[b][d][k] *= 1/Z[b][k], 8 consecutive k per thread
__global__ __launch_bounds__(256) void scale_vpt(
    short* __restrict__ vpT, const float* __restrict__ Z)
{
  const size_t base = ((size_t)blockIdx.x * 256 + threadIdx.x) * 8;  // < 2^22
  const int kk = (int)(base & (S_LEN - 1));
  const int b  = (int)(base >> 20);
  const float4 z0 = *(const float4*)&Z[(b << 11) + kk];
  const float4 z1 = *(const float4*)&Z[(b << 11) + kk + 4];
  s8v v = *(s8v*)&vpT[base];
  v[0] = f2bf_s(bf2f_s(v[0]) / z0.x); v[1] = f2bf_s(bf2f_s(v[1]) / z0.y);
  v[2] = f2bf_s(bf2f_s(v[2]) / z0.z); v[3] = f2bf_s(bf2f_s(v[3]) / z0.w);
  v[4] = f2bf_s(bf2f_s(v[4]) / z1.x); v[5] = f2bf_s(bf2f_s(v[5]) / z1.y);
  v[6] = f2bf_s(bf2f_s(v[6]) / z1.z); v[7] = f2bf_s(bf2f_s(v[7]) / z1.w);
  *(s8v*)&vpT[base] = v;
}

extern "C" void kernel_launch(void* const* d_in, const int* in_sizes, int n_in,
                              void* d_out, int out_size, void* d_ws, size_t ws_size,
                              hipStream_t stream) {
  const float* q   = (const float*)d_in[0];
  const float* k   = (const float*)d_in[1];
  const float* v   = (const float*)d_in[2];
  const float* WQw = (const float*)d_in[3];
  const float* WQb = (const float*)d_in[4];
  const float* WKw = (const float*)d_in[5];
  const float* WKb = (const float*)d_in[6];
  const float* WVw = (const float*)d_in[7];
  const float* WVb = (const float*)d_in[8];

  char* ws = (char*)d_ws;
  // E occupies [0,32M); bf16 input/weight copies alias its head (dead before E written)
  short* E   = (short*)(ws);                 // 32 MB  [4][2048][2048]
  short* qb  = (short*)(ws);                 //  8 MB  [8192][512]  (qb,kb,vb contiguous)
  short* Wqb = (short*)(ws + 25165824);      // 3x 512 KB contiguous
  short* qp  = (short*)(ws + 33554432);      //  8 MB  [4][2048][512]
  short* kp  = (short*)(ws + 41943040);      //  8 MB
  short* vpT = (short*)(ws + 50331648);      //  8 MB  [4][512][2048]
  float* Z   = (float*)(ws + 58720256);      // 32 KB  [4][2048]
  short* kb  = qb + 4194304;
  short* vb  = qb + 8388608;
  short* Wkb = Wqb + 262144;
  short* Wvb = Wqb + 524288;

  const dim3 blk(256);

  hipMemsetAsync(Z, 0, 4 * S_LEN * sizeof(float), stream);
  hipMemsetAsync(d_out, 0, (size_t)out_size * sizeof(float), stream);

  // converts: q/k/v (4.19M each), weights (262K each)
  cvt3<<<dim3(2048, 3), blk, 0, stream>>>(q, k, v, qb, 4194304);
  cvt3<<<dim3(128, 3), blk, 0, stream>>>(WQw, WKw, WVw, Wqb, 262144);

  // projections: M=8192, N=512, K=512 — one launch, 768 blocks
  proj3<<<dim3(4, 64, 3), blk, 0, stream>>>(
      qb, kb, vb, Wqb, Wkb, Wvb, qp, kp, vpT, WQb, WKb, WVb);

  // scores + mask + exp + fused column-sum: per batch M=N=2048, K=512
  gemm_nt<EPI_SCORES, 1><<<dim3(16, 16, 4), blk, 0, stream>>>(
      qp, kp, E, nullptr, 2048, 512,
      (long long)S_LEN * D_DIM, (long long)S_LEN * D_DIM, (long long)S_LEN * S_LEN, Z);

  // fold 1/Z into vp rows
  scale_vpt<<<dim3(2048), blk, 0, stream>>>(vpT, Z);

  // out = E @ vpT': per batch M=2048, N=512, K=2048, split-K=4 -> 1024 blocks
  gemm_nt<EPI_PLAIN, 4><<<dim3(4, 16, 16), blk, 0, stream>>>(
      E, vpT, d_out, nullptr, 512, 2048,
      (long long)S_LEN * S_LEN, (long long)D_DIM * S_LEN, (long long)S_LEN * D_DIM, nullptr);
}

// Round 5
// 204.503 us; speedup vs baseline: 1.2272x; 1.1537x over previous
//
#include <hip/hip_runtime.h>
#include <hip/hip_bf16.h>

// B=4, S=2048, D=512. fp32 in/out, bf16 MFMA internals.
//   cvt: q,k,v,W* fp32 -> bf16
//   proj3: qp = q@WQ^T+b, kp = k@WK^T+b, vpT = (v@WV^T+b)^T  (one launch, z=0..2)
//   scores: E = exp(mask(scale*qp@kp^T)) bf16, masked(q<k)=1; fused Z[k]=sum_q E[q][k]
//   scale:  vpT[b][d][k] /= Z[b][k]
//   out:    E @ vpT^T -> fp32, split-K=2: kz=0 -> d_out, kz=1 -> P (no atomics)
//   reduce: d_out += P
// GEMM core: 128x128 tile, BK=32, global_load_lds width-16 staging,
// XOR-swizzled column groups so ds_read_b128 is 2-way (free) in banks.

#define S_LEN 2048
#define D_DIM 512
#define SCALE_F 0.044194173824159216f  // 1/sqrt(512)

typedef __attribute__((ext_vector_type(8))) short s8v;   // 8 bf16 = 4 VGPRs
typedef __attribute__((ext_vector_type(4))) float f4v;   // MFMA accumulator

enum { EPI_BIAS = 0, EPI_BIAS_T = 1, EPI_SCORES = 2, EPI_PLAIN = 3 };

__device__ __forceinline__ short f2bf_s(float f) {
  union { __hip_bfloat16 b; short s; } u; u.b = __float2bfloat16(f); return u.s;
}
__device__ __forceinline__ float bf2f_s(short h) {
  union { short s; __hip_bfloat16 b; } u; u.s = h; return __bfloat162float(u.b);
}

__device__ __forceinline__ void glds16(const short* g, short* l) {
  __builtin_amdgcn_global_load_lds((const __attribute__((address_space(1))) void*)g,
                                   (__attribute__((address_space(3))) void*)l, 16, 0, 0);
}

// Core NT GEMM on a 128x128 tile at (m0,n0), K-range [kBeg,kEnd).
// A,B already offset to this batch. LDS As/Bs: 128x32 bf16, unpadded.
template <int EPI>
__device__ __forceinline__ void gemm_core(
    const short* __restrict__ A, const short* __restrict__ B,
    void* __restrict__ Cv, const float* __restrict__ bias,
    short* As, short* Bs,
    int N, int K, int kBeg, int kEnd,
    size_t sCz, int m0, int n0, int bz, float* __restrict__ Z)
{
  const int tid  = threadIdx.x;
  const int w    = tid >> 6;
  const int lane = tid & 63;
  const int quad = lane >> 4;
  const int l16  = lane & 15;
  const int wm   = (w >> 1) * 64;
  const int wn   = (w & 1) * 64;

  // staging: thread -> (row = tid>>2, phys 16B slot = tid&3); the slot holds
  // logical column-group g = slot ^ (r&3) ^ ((r>>2)&3)  (bank-conflict swizzle)
  const int sr = tid >> 2;                                            // 0..63
  const int g8 = (((tid & 3) ^ ((tid >> 2) & 3) ^ ((tid >> 4) & 3))) * 8;

  f4v acc[4][4];
#pragma unroll
  for (int i = 0; i < 4; ++i)
#pragma unroll
    for (int j = 0; j < 4; ++j)
#pragma unroll
      for (int r = 0; r < 4; ++r) acc[i][j][r] = 0.0f;

  const short* Ag = A + (size_t)(m0 + sr) * K + g8;
  const short* Bg = B + (size_t)(n0 + sr) * K + g8;
  short* Asl = As + tid * 8;
  short* Bsl = Bs + tid * 8;
  const size_t rowskip = (size_t)64 * K;

  // read-side swizzle: depends only on l16 (row mod 16)
  const int sw = ((l16 & 3) ^ ((l16 >> 2) & 3)) * 8;

  for (int k0 = kBeg; k0 < kEnd; k0 += 32) {
    glds16(Ag + k0,           Asl);
    glds16(Ag + k0 + rowskip, Asl + 2048);
    glds16(Bg + k0,           Bsl);
    glds16(Bg + k0 + rowskip, Bsl + 2048);
    __syncthreads();

    s8v af[4], bf[4];
#pragma unroll
    for (int i = 0; i < 4; ++i)
      af[i] = *(const s8v*)&As[(wm + i * 16 + l16) * 32 + ((quad * 8) ^ sw)];
#pragma unroll
    for (int j = 0; j < 4; ++j)
      bf[j] = *(const s8v*)&Bs[(wn + j * 16 + l16) * 32 + ((quad * 8) ^ sw)];

#pragma unroll
    for (int i = 0; i < 4; ++i)
#pragma unroll
      for (int j = 0; j < 4; ++j)
        acc[i][j] = __builtin_amdgcn_mfma_f32_16x16x32_bf16(af[i], bf[j], acc[i][j], 0, 0, 0);

    __syncthreads();
  }

  // ---- epilogue ----
  __hip_bfloat16* C = (__hip_bfloat16*)Cv;
  float* Cf = (float*)Cv;

  if (EPI == EPI_SCORES) {
#pragma unroll
    for (int j = 0; j < 4; ++j) {
      const int gn = n0 + wn + j * 16 + l16;
      float csum = 0.0f;
#pragma unroll
      for (int i = 0; i < 4; ++i) {
#pragma unroll
        for (int r = 0; r < 4; ++r) {
          const int gm = m0 + wm + i * 16 + quad * 4 + r;  // C/D: col=l16, row=quad*4+r
          const float e = (gm >= gn) ? __expf(acc[i][j][r] * SCALE_F) : 1.0f;
          csum += e;
          C[sCz + (size_t)gm * N + gn] = __float2bfloat16(e);
        }
      }
      csum += __shfl_xor(csum, 16, 64);
      csum += __shfl_xor(csum, 32, 64);
      if (quad == 0) atomicAdd(&Z[(bz << 11) + gn], csum);
    }
    return;
  }

  float bv[4];
  if (EPI == EPI_BIAS || EPI == EPI_BIAS_T) {
#pragma unroll
    for (int j = 0; j < 4; ++j) bv[j] = bias[n0 + wn + j * 16 + l16];
  }

#pragma unroll
  for (int i = 0; i < 4; ++i) {
#pragma unroll
    for (int j = 0; j < 4; ++j) {
      const int gn = n0 + wn + j * 16 + l16;
#pragma unroll
      for (int r = 0; r < 4; ++r) {
        const int gm = m0 + wm + i * 16 + quad * 4 + r;
        const float v = acc[i][j][r];
        if (EPI == EPI_BIAS) {
          C[(size_t)gm * N + gn] = __float2bfloat16(v + bv[j]);
        } else if (EPI == EPI_BIAS_T) {
          const int bb = gm >> 11, ss = gm & (S_LEN - 1);
          C[((size_t)bb * D_DIM + gn) * S_LEN + ss] = __float2bfloat16(v + bv[j]);
        } else {  // EPI_PLAIN: plain fp32 store (split-K halves go to disjoint buffers)
          Cf[sCz + (size_t)gm * N + gn] = v;
        }
      }
    }
  }
}

template <int EPI, int KSPLIT>
__global__ __launch_bounds__(256, 2) void gemm_nt(
    const short* __restrict__ A, const short* __restrict__ B,
    void* __restrict__ Cv, void* __restrict__ Cv2, const float* __restrict__ bias,
    int N, int K, long long sA, long long sB, long long sC,
    float* __restrict__ Z)
{
  __shared__ __align__(16) short As[128 * 32];
  __shared__ __align__(16) short Bs[128 * 32];
  const int z  = blockIdx.z;
  const int bz = z / KSPLIT, kz = z % KSPLIT;
  const int KS = K / KSPLIT;
  void* dst = (kz == 0) ? Cv : Cv2;
  gemm_core<EPI>(A + (size_t)bz * sA, B + (size_t)bz * sB, dst, bias, As, Bs,
                 N, K, kz * KS, kz * KS + KS, (size_t)bz * sC,
                 blockIdx.y * 128, blockIdx.x * 128, bz, Z);
}

// three projections in one launch: z=0 -> qp, z=1 -> kp, z=2 -> vpT (transposed write)
__global__ __launch_bounds__(256, 2) void proj3(
    const short* __restrict__ a0, const short* __restrict__ a1, const short* __restrict__ a2,
    const short* __restrict__ b0, const short* __restrict__ b1, const short* __restrict__ b2,
    short* __restrict__ c0, short* __restrict__ c1, short* __restrict__ c2,
    const float* __restrict__ x0, const float* __restrict__ x1, const float* __restrict__ x2)
{
  __shared__ __align__(16) short As[128 * 32];
  __shared__ __align__(16) short Bs[128 * 32];
  const int z = blockIdx.z;
  const short* A = (z == 0) ? a0 : (z == 1) ? a1 : a2;
  const short* B = (z == 0) ? b0 : (z == 1) ? b1 : b2;
  void*        C = (z == 0) ? (void*)c0 : (z == 1) ? (void*)c1 : (void*)c2;
  const float* bias = (z == 0) ? x0 : (z == 1) ? x1 : x2;
  if (z == 2)
    gemm_core<EPI_BIAS_T>(A, B, C, bias, As, Bs, 512, 512, 0, 512, 0,
                          blockIdx.y * 128, blockIdx.x * 128, 0, nullptr);
  else
    gemm_core<EPI_BIAS>(A, B, C, bias, As, Bs, 512, 512, 0, 512, 0,
                        blockIdx.y * 128, blockIdx.x * 128, 0, nullptr);
}

// fp32 -> bf16, 8 elems/thread, three source arrays -> contiguous dst slabs
__global__ __launch_bounds__(256) void cvt3(
    const float* __restrict__ s0, const float* __restrict__ s1,
    const float* __restrict__ s2, short* __restrict__ dst, int n)
{
  const float* s = (blockIdx.y == 0) ? s0 : (blockIdx.y == 1) ? s1 : s2;
  short* d = dst + (size_t)blockIdx.y * n;
  const int i = (blockIdx.x * 256 + threadIdx.x) * 8;
  if (i >= n) return;
  const float4 f0 = *(const float4*)(s + i);
  const float4 f1 = *(const float4*)(s + i + 4);
  s8v o;
  o[0] = f2bf_s(f0.x); o[1] = f2bf_s(f0.y); o[2] = f2bf_s(f0.z); o[3] = f2bf_s(f0.w);
  o[4] = f2bf_s(f1.x); o[5] = f2bf_s(f1.y); o[6] = f2bf_s(f1.z); o[7] = f2bf_s(f1.w);
  *(s8v*)(d + i) = o;
}

// vpT[b][d][k] *= 1/Z[b][k], 8 consecutive k per thread
__global__ __launch_bounds__(256) void scale_vpt(
    short* __restrict__ vpT, const float* __restrict__ Z)
{
  const size_t base = ((size_t)blockIdx.x * 256 + threadIdx.x) * 8;  // < 2^22
  const int kk = (int)(base & (S_LEN - 1));
  const int b  = (int)(base >> 20);
  const float4 z0 = *(const float4*)&Z[(b << 11) + kk];
  const float4 z1 = *(const float4*)&Z[(b << 11) + kk + 4];
  s8v v = *(s8v*)&vpT[base];
  v[0] = f2bf_s(bf2f_s(v[0]) / z0.x); v[1] = f2bf_s(bf2f_s(v[1]) / z0.y);
  v[2] = f2bf_s(bf2f_s(v[2]) / z0.z); v[3] = f2bf_s(bf2f_s(v[3]) / z0.w);
  v[4] = f2bf_s(bf2f_s(v[4]) / z1.x); v[5] = f2bf_s(bf2f_s(v[5]) / z1.y);
  v[6] = f2bf_s(bf2f_s(v[6]) / z1.z); v[7] = f2bf_s(bf2f_s(v[7]) / z1.w);
  *(s8v*)&vpT[base] = v;
}

// d_out += P, one float4 per thread
__global__ __launch_bounds__(256) void add_reduce(
    float* __restrict__ out, const float* __restrict__ P)
{
  const size_t i = ((size_t)blockIdx.x * 256 + threadIdx.x) * 4;
  float4 a = *(const float4*)(out + i);
  const float4 b = *(const float4*)(P + i);
  a.x += b.x; a.y += b.y; a.z += b.z; a.w += b.w;
  *(float4*)(out + i) = a;
}

extern "C" void kernel_launch(void* const* d_in, const int* in_sizes, int n_in,
                              void* d_out, int out_size, void* d_ws, size_t ws_size,
                              hipStream_t stream) {
  const float* q   = (const float*)d_in[0];
  const float* k   = (const float*)d_in[1];
  const float* v   = (const float*)d_in[2];
  const float* WQw = (const float*)d_in[3];
  const float* WQb = (const float*)d_in[4];
  const float* WKw = (const float*)d_in[5];
  const float* WKb = (const float*)d_in[6];
  const float* WVw = (const float*)d_in[7];
  const float* WVb = (const float*)d_in[8];

  char* ws = (char*)d_ws;
  // E occupies [0,32M); bf16 input/weight copies alias its head (dead before E written)
  short* E   = (short*)(ws);                 // 32 MB  [4][2048][2048]
  short* qb  = (short*)(ws);                 //  8 MB  [8192][512]  (qb,kb,vb contiguous)
  short* Wqb = (short*)(ws + 25165824);      // 3x 512 KB contiguous
  short* qp  = (short*)(ws + 33554432);      //  8 MB  [4][2048][512]
  short* kp  = (short*)(ws + 41943040);      //  8 MB
  float* P   = (float*)(ws + 33554432);      // 16 MB split-K partial (aliases dead qp+kp)
  short* vpT = (short*)(ws + 50331648);      //  8 MB  [4][512][2048]
  float* Z   = (float*)(ws + 58720256);      // 32 KB  [4][2048]
  short* kb  = qb + 4194304;
  short* vb  = qb + 8388608;
  short* Wkb = Wqb + 262144;
  short* Wvb = Wqb + 524288;

  const dim3 blk(256);

  hipMemsetAsync(Z, 0, 4 * S_LEN * sizeof(float), stream);

  // converts: q/k/v (4.19M each), weights (262K each)
  cvt3<<<dim3(2048, 3), blk, 0, stream>>>(q, k, v, qb, 4194304);
  cvt3<<<dim3(128, 3), blk, 0, stream>>>(WQw, WKw, WVw, Wqb, 262144);

  // projections: M=8192, N=512, K=512 — one launch, 768 blocks
  proj3<<<dim3(4, 64, 3), blk, 0, stream>>>(
      qb, kb, vb, Wqb, Wkb, Wvb, qp, kp, vpT, WQb, WKb, WVb);

  // scores + mask + exp + fused column-sum: per batch M=N=2048, K=512
  gemm_nt<EPI_SCORES, 1><<<dim3(16, 16, 4), blk, 0, stream>>>(
      qp, kp, E, nullptr, nullptr, 2048, 512,
      (long long)S_LEN * D_DIM, (long long)S_LEN * D_DIM, (long long)S_LEN * S_LEN, Z);

  // fold 1/Z into vp rows
  scale_vpt<<<dim3(2048), blk, 0, stream>>>(vpT, Z);

  // out = E @ vpT': per batch M=2048, N=512, K=2048, split-K=2 -> 512 blocks
  // kz=0 -> d_out (plain stores), kz=1 -> P; then d_out += P
  gemm_nt<EPI_PLAIN, 2><<<dim3(4, 16, 8), blk, 0, stream>>>(
      E, vpT, d_out, P, nullptr, 512, 2048,
      (long long)S_LEN * S_LEN, (long long)D_DIM * S_LEN, (long long)S_LEN * D_DIM, nullptr);

  add_reduce<<<dim3(4096), blk, 0, stream>>>((float*)d_out, P);
}